// Round 1
// 256.787 us; speedup vs baseline: 1.0634x; 1.0634x over previous
//
#include <hip/hip_runtime.h>
#include <hip/hip_bf16.h>

#define NN 32768
#define EE 524288
#define GG 256
#define PP 128
// fixed-capacity CSR bucket: 64 slots/node (P(deg>64) ~ 1e-55 for Poisson(16))

// ---------------------------------------------------------------------------
// k_init: blocks 0..8191 -> h = normalize(relu(x @ W1.T + b1)), wave/node;
//         these blocks also prefill csr bucket with sentinel NN (64 int4 each)
//         and blocks < 128 zero deg[].
//         blocks 8192..8223 -> fold W2/W3/W4/biases into Wc[kk][o] + c.
//         block 8224 -> transpose Wd1 -> Wd1t.
//         block 8225 -> zero sentinel row NN of h0 and h1 (gather pad target).
// ---------------------------------------------------------------------------
__global__ void k_init(const float* __restrict__ x, const float* __restrict__ W1,
                       const float* __restrict__ b1,
                       const float* __restrict__ W2, const float* __restrict__ b2,
                       const float* __restrict__ W3, const float* __restrict__ b3,
                       const float* __restrict__ W4, const float* __restrict__ b4,
                       const float* __restrict__ Wd1,
                       float* __restrict__ h0, float* __restrict__ h1,
                       float* __restrict__ Wc, float* __restrict__ Wd1t,
                       int* __restrict__ deg, int* __restrict__ csr) {
    __shared__ float tile[128 * 65];
    int b = blockIdx.x, t = threadIdx.x;
    if (b >= 8192) {
        if (b == 8224) {                       // Wd1 transpose
            for (int idx = t; idx < 8192; idx += 256) {
                int q = idx >> 6, o = idx & 63;
                tile[q*65 + o] = Wd1[idx];
            }
            __syncthreads();
            for (int idx = t; idx < 8192; idx += 256) {
                int o = idx >> 7, q = idx & 127;
                Wd1t[idx] = tile[q*65 + o];
            }
        } else if (b == 8225) {                // zero sentinel rows
            if (t < 64)       h0[(long)NN*64 + t] = 0.f;
            else if (t < 128) h1[(long)NN*64 + (t-64)] = 0.f;
        } else {                               // Wc fold
            int idx = (b - 8192) * 256 + t;    // 0..8191
            int kk = idx >> 6, o = idx & 63;
            float a = 0.f;
            if (kk < 64) {
                for (int j = 0; j < 64; ++j) a += W4[o*128 + j] * W3[j*64 + kk];
            } else {
                int k2 = kk - 64;
                for (int j = 0; j < 64; ++j) a += W4[o*128 + 64 + j] * W2[j*64 + k2];
            }
            Wc[kk*64 + o] = a;
            if (idx < 64) {
                float c = b4[idx];
                for (int j = 0; j < 64; ++j)
                    c += W4[idx*128 + j]*b3[j] + W4[idx*128 + 64 + j]*b2[j];
                Wc[8192 + idx] = c;
            }
        }
        return;
    }
    if (b < 128) deg[b * 256 + t] = 0;
    if (t < 64)  // csr bucket sentinel prefill: 64 int4 per block x 8192 blocks
        ((int4*)csr)[b*64 + t] = make_int4(NN, NN, NN, NN);
    int node = (b * 256 + t) >> 6;
    int lane = t & 63;
    float acc = b1[lane];
    #pragma unroll
    for (int j = 0; j < 8; ++j)
        acc += x[node*8 + j] * W1[lane*8 + j];
    acc = fmaxf(acc, 0.f);
    float ss = acc * acc;
    #pragma unroll
    for (int m = 1; m < 64; m <<= 1) ss += __shfl_xor(ss, m, 64);
    h0[node*64 + lane] = acc / sqrtf(ss);
}

// ---------------------------------------------------------------------------
// k_fill: direct bucket CSR build (replaces hist+scan+fill).
// csr[dst*64 + pos] = src; deg[dst] counts. Slot order nondeterministic
// (harmless: segment-sum order was already nondeterministic).
// ---------------------------------------------------------------------------
__global__ void k_fill(const int* __restrict__ src, const int* __restrict__ dst,
                       int* __restrict__ deg, int* __restrict__ csr) {
    int i = blockIdx.x * blockDim.x + threadIdx.x;   // 131072 threads
    int4 s4 = ((const int4*)src)[i];
    int4 d4 = ((const int4*)dst)[i];
    csr[(d4.x << 6) + atomicAdd(&deg[d4.x], 1)] = s4.x;
    csr[(d4.y << 6) + atomicAdd(&deg[d4.y], 1)] = s4.y;
    csr[(d4.z << 6) + atomicAdd(&deg[d4.z], 1)] = s4.z;
    csr[(d4.w << 6) + atomicAdd(&deg[d4.w], 1)] = s4.w;
}

// ---------------------------------------------------------------------------
// k_layer: FUSED gather + gemm. One block = 64 nodes (512 blocks, 2/CU).
//
// Phase A: stage Wc->LDS, stage h-half of X->LDS, and gather the message
//   half of X directly into LDS (no global m round-trip).
//   Gather mapping: wave w owns nodes w*16..w*16+15, one node at a time.
//   Lane split per node: fg4=(lane&15)*4 features, es=lane>>4 slot-group.
//   TWO unconditional int4 slot-rounds per node (slots 0..31; covers
//   deg<=32; pad slots hold sentinel NN whose h-row is zero => exact +0.f
//   and L1-hot). Index int4s prefetched one node ahead. Each float4 gather
//   instruction covers 4 rows (one per es-group) => ~32 rows in flight per
//   wave, enough latency hiding at 8 waves/CU. Rare deg>32 tail (P~1e-4)
//   handled by a wave-uniform branch, keeping results exact.
//
// Phase B: hn[n][o] = normalize(relu(sum_kk X[n][kk]*Wc[kk][o] + c[o])),
//   X = [m | h], thread tile 4n x 4o (identical to previous k_gemm).
// ---------------------------------------------------------------------------
__global__ void __launch_bounds__(256) k_layer(
        const float* __restrict__ Wc, const float* __restrict__ hcur,
        const int* __restrict__ deg, const int* __restrict__ csr,
        float* __restrict__ hnext) {
    __shared__ float Wl[8192];       // [kk][o], stride 64
    __shared__ float Xl[64 * 132];   // [n][kk], stride 132
    int t = threadIdx.x;
    int nbase = blockIdx.x * 64;

    for (int i = t * 4; i < 8192; i += 1024)
        *(float4*)&Wl[i] = *(const float4*)&Wc[i];
    for (int idx = t; idx < 1024; idx += 256) {
        int n = idx >> 4, c = (idx & 15) * 4;
        *(float4*)&Xl[n*132 + 64 + c] = *(const float4*)&hcur[(long)(nbase+n)*64 + c];
    }

    // ---- Phase A: gather messages into Xl[n][0..63] ----
    int w = t >> 6, lane = t & 63;
    int fg4 = (lane & 15) * 4, es = lane >> 4;
    int nb = nbase + w * 16;
    int dv = deg[nb + (lane & 15)];          // 16 degs, one coalesced line
    const int4* base4 = (const int4*)csr + (long)nb * 16;
    int4 iA = base4[es];                     // node 0, slot-round 0 (q=es)
    int4 iB = base4[4 + es];                 // node 0, slot-round 1 (q=es+4)
    for (int ni = 0; ni < 16; ++ni) {
        int4 cA = iA, cB = iB;
        if (ni < 15) {                       // prefetch next node's indices
            iA = base4[(ni+1)*16 + es];
            iB = base4[(ni+1)*16 + 4 + es];
        }
        float4 a0 = *(const float4*)&hcur[(long)cA.x*64 + fg4];
        float4 a1 = *(const float4*)&hcur[(long)cA.y*64 + fg4];
        float4 a2 = *(const float4*)&hcur[(long)cA.z*64 + fg4];
        float4 a3 = *(const float4*)&hcur[(long)cA.w*64 + fg4];
        float4 b0 = *(const float4*)&hcur[(long)cB.x*64 + fg4];
        float4 b1 = *(const float4*)&hcur[(long)cB.y*64 + fg4];
        float4 b2 = *(const float4*)&hcur[(long)cB.z*64 + fg4];
        float4 b3 = *(const float4*)&hcur[(long)cB.w*64 + fg4];
        float4 acc;
        acc.x = ((a0.x + a1.x) + (a2.x + a3.x)) + ((b0.x + b1.x) + (b2.x + b3.x));
        acc.y = ((a0.y + a1.y) + (a2.y + a3.y)) + ((b0.y + b1.y) + (b2.y + b3.y));
        acc.z = ((a0.z + a1.z) + (a2.z + a3.z)) + ((b0.z + b1.z) + (b2.z + b3.z));
        acc.w = ((a0.w + a1.w) + (a2.w + a3.w)) + ((b0.w + b1.w) + (b2.w + b3.w));
        int dg = __shfl(dv, ni, 64);
        if (dg > 32) {                       // rare exact tail (deg 33..64)
            int de4 = (dg + 3) >> 2;
            for (int q = es + 8; q < de4; q += 4) {
                int4 cx = base4[ni*16 + q];
                float4 v0 = *(const float4*)&hcur[(long)cx.x*64 + fg4];
                float4 v1 = *(const float4*)&hcur[(long)cx.y*64 + fg4];
                float4 v2 = *(const float4*)&hcur[(long)cx.z*64 + fg4];
                float4 v3 = *(const float4*)&hcur[(long)cx.w*64 + fg4];
                acc.x += (v0.x + v1.x) + (v2.x + v3.x);
                acc.y += (v0.y + v1.y) + (v2.y + v3.y);
                acc.z += (v0.z + v1.z) + (v2.z + v3.z);
                acc.w += (v0.w + v1.w) + (v2.w + v3.w);
            }
        }
        acc.x += __shfl_xor(acc.x, 16, 64); acc.y += __shfl_xor(acc.y, 16, 64);
        acc.z += __shfl_xor(acc.z, 16, 64); acc.w += __shfl_xor(acc.w, 16, 64);
        acc.x += __shfl_xor(acc.x, 32, 64); acc.y += __shfl_xor(acc.y, 32, 64);
        acc.z += __shfl_xor(acc.z, 32, 64); acc.w += __shfl_xor(acc.w, 32, 64);
        if (es == 0) *(float4*)&Xl[(w*16 + ni)*132 + fg4] = acc;
    }
    __syncthreads();

    // ---- Phase B: gemm ----
    int tc = t & 15, tr = t >> 4;
    int o0 = tc * 4, n0 = tr * 4;
    float4 c4 = *(const float4*)&Wc[8192 + o0];
    float acc[4][4] = {};
    #pragma unroll 2
    for (int kk = 0; kk < 128; kk += 4) {
        float4 w0 = *(float4*)&Wl[(kk+0)*64 + o0];
        float4 w1 = *(float4*)&Wl[(kk+1)*64 + o0];
        float4 w2 = *(float4*)&Wl[(kk+2)*64 + o0];
        float4 w3 = *(float4*)&Wl[(kk+3)*64 + o0];
        #pragma unroll
        for (int jn = 0; jn < 4; ++jn) {
            float4 xv = *(float4*)&Xl[(n0+jn)*132 + kk];
            acc[jn][0] += xv.x*w0.x + xv.y*w1.x + xv.z*w2.x + xv.w*w3.x;
            acc[jn][1] += xv.x*w0.y + xv.y*w1.y + xv.z*w2.y + xv.w*w3.y;
            acc[jn][2] += xv.x*w0.z + xv.y*w1.z + xv.z*w2.z + xv.w*w3.z;
            acc[jn][3] += xv.x*w0.w + xv.y*w1.w + xv.z*w2.w + xv.w*w3.w;
        }
    }

    #pragma unroll
    for (int jn = 0; jn < 4; ++jn) {
        float v0 = fmaxf(acc[jn][0] + c4.x, 0.f);
        float v1 = fmaxf(acc[jn][1] + c4.y, 0.f);
        float v2 = fmaxf(acc[jn][2] + c4.z, 0.f);
        float v3 = fmaxf(acc[jn][3] + c4.w, 0.f);
        float ss = v0*v0 + v1*v1 + v2*v2 + v3*v3;
        ss += __shfl_xor(ss, 1, 64);
        ss += __shfl_xor(ss, 2, 64);
        ss += __shfl_xor(ss, 4, 64);
        ss += __shfl_xor(ss, 8, 64);
        float r = 1.0f / sqrtf(ss);
        float4 outv = make_float4(v0*r, v1*r, v2*r, v3*r);
        *(float4*)&hnext[(long)(nbase + n0 + jn)*64 + o0] = outv;
    }
}

// ---------------------------------------------------------------------------
// k_tmat: Tt[g][i*64+o] = sum_j W5[o][i*64+j] * last[g][j].
// 256 blocks = 16 consecutive rows r = i*64+o each; thread = graph.
// ---------------------------------------------------------------------------
__global__ void __launch_bounds__(256) k_tmat(
        const float* __restrict__ h, const float* __restrict__ W5,
        float* __restrict__ Tt) {
    __shared__ float lastL[256 * 65];   // 66.6 KB
    __shared__ float wL[64 * 16];       // [j][rr]
    __shared__ float tr[16 * 257];      // [rr][g]
    int t = threadIdx.x;
    int rb = blockIdx.x * 16;
    int i = rb >> 6, obase = rb & 63;

    for (int idx4 = t; idx4 < 4096; idx4 += 256) {
        int g = idx4 >> 4, c = (idx4 & 15) * 4;
        *(float4*)&lastL[g*65 + c] =
            *(const float4*)&h[((long)g*128 + 127)*64 + c];
    }
    {   // stage W5 slice, transposed to [j][rr]
        int rr = t & 15, j0 = (t >> 4) * 4;
        float4 w = *(const float4*)&W5[(long)(obase + rr)*4096 + i*64 + j0];
        wL[(j0+0)*16 + rr] = w.x;
        wL[(j0+1)*16 + rr] = w.y;
        wL[(j0+2)*16 + rr] = w.z;
        wL[(j0+3)*16 + rr] = w.w;
    }
    __syncthreads();

    int g = t;
    float acc[16] = {};
    for (int j = 0; j < 64; ++j) {
        float lv = lastL[g*65 + j];
        #pragma unroll
        for (int r4 = 0; r4 < 4; ++r4) {
            float4 wv = *(float4*)&wL[j*16 + r4*4];
            acc[r4*4+0] += wv.x * lv;
            acc[r4*4+1] += wv.y * lv;
            acc[r4*4+2] += wv.z * lv;
            acc[r4*4+3] += wv.w * lv;
        }
    }
    #pragma unroll
    for (int rr = 0; rr < 16; ++rr) tr[rr*257 + g] = acc[rr];
    __syncthreads();
    for (int it = 0; it < 4; ++it) {
        int idx = t + it*256;
        int g2 = idx >> 2, c4 = idx & 3;
        float4 v = make_float4(tr[(c4*4+0)*257 + g2], tr[(c4*4+1)*257 + g2],
                               tr[(c4*4+2)*257 + g2], tr[(c4*4+3)*257 + g2]);
        *(float4*)&Tt[(long)g2*4096 + rb + c4*4] = v;
    }
}

// ---------------------------------------------------------------------------
// k_readout: ONE block per graph (256 blocks), 4 p-tiles of 32.
// T and Wd1t staged once per graph (was twice).
// ---------------------------------------------------------------------------
__global__ void __launch_bounds__(256) k_readout(
        const float* __restrict__ h, const float* __restrict__ Tt,
        const float* __restrict__ b5, const float* __restrict__ Wd1t,
        const float* __restrict__ bd1, const float* __restrict__ Wd2,
        const float* __restrict__ bd2, float* __restrict__ out) {
    __shared__ float Tl[4096];       // [i][o], stride 64
    __shared__ float W1t[8192];      // [o][q], stride 128
    __shared__ float OY[32 * 68];    // [p][i] then [p][o], stride 68
    int t = threadIdx.x;
    int g = blockIdx.x;

    for (int i = t * 4; i < 4096; i += 1024)
        *(float4*)&Tl[i] = *(const float4*)&Tt[(long)g*4096 + i];
    for (int i = t * 4; i < 8192; i += 1024)
        *(float4*)&W1t[i] = *(const float4*)&Wd1t[i];

    int tc = t & 15, tr = t >> 4;      // GEMM1 map
    int o0 = tc * 4, p0 = tr * 2;
    int tc2 = t & 31, tr2 = t >> 5;    // GEMM2 map
    int q0 = tc2 * 4, pp0 = tr2 * 4;
    float4 b5_4  = *(const float4*)&b5[o0];
    float4 bd1_4 = *(const float4*)&bd1[q0];
    float4 wd2_4 = *(const float4*)&Wd2[q0];
    float bd2v = bd2[0];

    for (int pt = 0; pt < 4; ++pt) {
        int pbase = pt * 32;
        __syncthreads();  // previous tile's GEMM2 reads done; T/W1t staged
        for (int idx = t; idx < 512; idx += 256) {
            int p = idx >> 4, c = (idx & 15) * 4;
            *(float4*)&OY[p*68 + c] =
                *(const float4*)&h[((long)g*128 + pbase + p)*64 + c];
        }
        __syncthreads();

        // GEMM1
        float a10[4] = {0.f,0.f,0.f,0.f};
        float a11[4] = {0.f,0.f,0.f,0.f};
        #pragma unroll 4
        for (int i = 0; i < 64; i += 4) {
            float4 w0 = *(float4*)&Tl[(i+0)*64 + o0];
            float4 w1 = *(float4*)&Tl[(i+1)*64 + o0];
            float4 w2 = *(float4*)&Tl[(i+2)*64 + o0];
            float4 w3 = *(float4*)&Tl[(i+3)*64 + o0];
            float4 x0 = *(float4*)&OY[(p0+0)*68 + i];
            float4 x1 = *(float4*)&OY[(p0+1)*68 + i];
            a10[0] += x0.x*w0.x + x0.y*w1.x + x0.z*w2.x + x0.w*w3.x;
            a10[1] += x0.x*w0.y + x0.y*w1.y + x0.z*w2.y + x0.w*w3.y;
            a10[2] += x0.x*w0.z + x0.y*w1.z + x0.z*w2.z + x0.w*w3.z;
            a10[3] += x0.x*w0.w + x0.y*w1.w + x0.z*w2.w + x0.w*w3.w;
            a11[0] += x1.x*w0.x + x1.y*w1.x + x1.z*w2.x + x1.w*w3.x;
            a11[1] += x1.x*w0.y + x1.y*w1.y + x1.z*w2.y + x1.w*w3.y;
            a11[2] += x1.x*w0.z + x1.y*w1.z + x1.z*w2.z + x1.w*w3.z;
            a11[3] += x1.x*w0.w + x1.y*w1.w + x1.z*w2.w + x1.w*w3.w;
        }
        __syncthreads();  // all reads of O done; OY becomes Y

        float4 y0 = make_float4(a10[0]+b5_4.x, a10[1]+b5_4.y, a10[2]+b5_4.z, a10[3]+b5_4.w);
        float4 y1 = make_float4(a11[0]+b5_4.x, a11[1]+b5_4.y, a11[2]+b5_4.z, a11[3]+b5_4.w);
        *(float4*)&OY[(p0+0)*68 + o0] = y0;
        *(float4*)&OY[(p0+1)*68 + o0] = y1;
        __syncthreads();

        // GEMM2
        float a2[4][4] = {};
        #pragma unroll 4
        for (int o = 0; o < 64; o += 4) {
            float4 w0 = *(float4*)&W1t[(o+0)*128 + q0];
            float4 w1 = *(float4*)&W1t[(o+1)*128 + q0];
            float4 w2 = *(float4*)&W1t[(o+2)*128 + q0];
            float4 w3 = *(float4*)&W1t[(o+3)*128 + q0];
            #pragma unroll
            for (int jp = 0; jp < 4; ++jp) {
                float4 yv = *(float4*)&OY[(pp0+jp)*68 + o];
                a2[jp][0] += yv.x*w0.x + yv.y*w1.x + yv.z*w2.x + yv.w*w3.x;
                a2[jp][1] += yv.x*w0.y + yv.y*w1.y + yv.z*w2.y + yv.w*w3.y;
                a2[jp][2] += yv.x*w0.z + yv.y*w1.z + yv.z*w2.z + yv.w*w3.z;
                a2[jp][3] += yv.x*w0.w + yv.y*w1.w + yv.z*w2.w + yv.w*w3.w;
            }
        }

        #pragma unroll
        for (int jp = 0; jp < 4; ++jp) {
            float s = wd2_4.x * fmaxf(a2[jp][0] + bd1_4.x, 0.f)
                    + wd2_4.y * fmaxf(a2[jp][1] + bd1_4.y, 0.f)
                    + wd2_4.z * fmaxf(a2[jp][2] + bd1_4.z, 0.f)
                    + wd2_4.w * fmaxf(a2[jp][3] + bd1_4.w, 0.f);
            s += __shfl_xor(s, 1, 64);
            s += __shfl_xor(s, 2, 64);
            s += __shfl_xor(s, 4, 64);
            s += __shfl_xor(s, 8, 64);
            s += __shfl_xor(s, 16, 64);
            if (tc2 == 0) {
                int p = pbase + pp0 + jp;
                if (p < 127) out[g*127 + p] = s + bd2v;
            }
        }
    }
}

extern "C" void kernel_launch(void* const* d_in, const int* in_sizes, int n_in,
                              void* d_out, int out_size, void* d_ws, size_t ws_size,
                              hipStream_t stream) {
    const float* x   = (const float*)d_in[0];
    const int*   ei  = (const int*)d_in[1];   // [2][E] int32
    const float* W1  = (const float*)d_in[4];
    const float* b1  = (const float*)d_in[5];
    const float* W2  = (const float*)d_in[6];
    const float* b2  = (const float*)d_in[7];
    const float* W3  = (const float*)d_in[8];
    const float* b3  = (const float*)d_in[9];
    const float* W4  = (const float*)d_in[10];
    const float* b4  = (const float*)d_in[11];
    const float* W5  = (const float*)d_in[12];
    const float* b5  = (const float*)d_in[13];
    const float* Wd1 = (const float*)d_in[14];
    const float* bd1 = (const float*)d_in[15];
    const float* Wd2 = (const float*)d_in[16];
    const float* bd2 = (const float*)d_in[17];
    float* out = (float*)d_out;

    float* ws  = (float*)d_ws;
    float* h0   = ws;                        // (NN+1)*64 floats (row NN = zeros)
    float* h1   = ws + 2129984;              // (NN+1)*64 floats, 16-aligned
    float* Tt   = ws + 4259968;              // 2^20 floats
    float* Wc   = ws + 5308416;              // 8448 floats
    float* Wd1t = ws + 5316864;              // 8192 floats
    int*   deg  = (int*)(ws + 5325056);      // NN
    int*   csr  = deg + NN;                  // NN*64 ints (bucket CSR)

    const int* src = ei;
    const int* dst = ei + EE;

    k_init<<<8226, 256, 0, stream>>>(x, W1, b1, W2, b2, W3, b3, W4, b4,
                                     Wd1, h0, h1, Wc, Wd1t, deg, csr);
    k_fill<<<512, 256, 0, stream>>>(src, dst, deg, csr);

    float* hc = h0; float* hn = h1;
    for (int l = 0; l < 3; ++l) {
        // fused gather+gemm: messages never touch global memory; hn gets
        // the updated features. Sentinel row NN of both buffers stays zero.
        k_layer<<<NN/64, 256, 0, stream>>>(Wc, hc, deg, csr, hn);
        float* tmp = hc; hc = hn; hn = tmp;
    }

    k_tmat<<<256, 256, 0, stream>>>(hc, W5, Tt);
    k_readout<<<256, 256, 0, stream>>>(hc, Tt, b5, Wd1t, bd1, Wd2, bd2, out);
}

// Round 2
// 253.326 us; speedup vs baseline: 1.0779x; 1.0137x over previous
//
#include <hip/hip_runtime.h>
#include <hip/hip_bf16.h>

#define NN 32768
#define EE 524288
#define GG 256
#define PP 128
// fixed-capacity CSR bucket: 64 slots/node (P(deg>64) ~ 1e-55 for Poisson(16))

// ---------------------------------------------------------------------------
// k_init: blocks 0..8191 -> h = normalize(relu(x @ W1.T + b1)), wave/node;
//         these blocks also prefill csr bucket with sentinel NN (64 int4 each)
//         and blocks < 128 zero deg[].
//         blocks 8192..8223 -> fold W2/W3/W4/biases into Wc[kk][o] + c.
//         block 8224 -> transpose Wd1 -> Wd1t.
//         block 8225 -> zero sentinel row NN of h0 and h1 (gather pad target).
// ---------------------------------------------------------------------------
__global__ void k_init(const float* __restrict__ x, const float* __restrict__ W1,
                       const float* __restrict__ b1,
                       const float* __restrict__ W2, const float* __restrict__ b2,
                       const float* __restrict__ W3, const float* __restrict__ b3,
                       const float* __restrict__ W4, const float* __restrict__ b4,
                       const float* __restrict__ Wd1,
                       float* __restrict__ h0, float* __restrict__ h1,
                       float* __restrict__ Wc, float* __restrict__ Wd1t,
                       int* __restrict__ deg, int* __restrict__ csr) {
    __shared__ float tile[128 * 65];
    int b = blockIdx.x, t = threadIdx.x;
    if (b >= 8192) {
        if (b == 8224) {                       // Wd1 transpose
            for (int idx = t; idx < 8192; idx += 256) {
                int q = idx >> 6, o = idx & 63;
                tile[q*65 + o] = Wd1[idx];
            }
            __syncthreads();
            for (int idx = t; idx < 8192; idx += 256) {
                int o = idx >> 7, q = idx & 127;
                Wd1t[idx] = tile[q*65 + o];
            }
        } else if (b == 8225) {                // zero sentinel rows
            if (t < 64)       h0[(long)NN*64 + t] = 0.f;
            else if (t < 128) h1[(long)NN*64 + (t-64)] = 0.f;
        } else {                               // Wc fold
            int idx = (b - 8192) * 256 + t;    // 0..8191
            int kk = idx >> 6, o = idx & 63;
            float a = 0.f;
            if (kk < 64) {
                for (int j = 0; j < 64; ++j) a += W4[o*128 + j] * W3[j*64 + kk];
            } else {
                int k2 = kk - 64;
                for (int j = 0; j < 64; ++j) a += W4[o*128 + 64 + j] * W2[j*64 + k2];
            }
            Wc[kk*64 + o] = a;
            if (idx < 64) {
                float c = b4[idx];
                for (int j = 0; j < 64; ++j)
                    c += W4[idx*128 + j]*b3[j] + W4[idx*128 + 64 + j]*b2[j];
                Wc[8192 + idx] = c;
            }
        }
        return;
    }
    if (b < 128) deg[b * 256 + t] = 0;
    if (t < 64)  // csr bucket sentinel prefill: 64 int4 per block x 8192 blocks
        ((int4*)csr)[b*64 + t] = make_int4(NN, NN, NN, NN);
    int node = (b * 256 + t) >> 6;
    int lane = t & 63;
    float acc = b1[lane];
    #pragma unroll
    for (int j = 0; j < 8; ++j)
        acc += x[node*8 + j] * W1[lane*8 + j];
    acc = fmaxf(acc, 0.f);
    float ss = acc * acc;
    #pragma unroll
    for (int m = 1; m < 64; m <<= 1) ss += __shfl_xor(ss, m, 64);
    h0[node*64 + lane] = acc / sqrtf(ss);
}

// ---------------------------------------------------------------------------
// k_fill: direct bucket CSR build.
// csr[dst*64 + pos] = src; deg[dst] counts. Slot order nondeterministic
// (harmless: segment-sum order was already nondeterministic).
// ---------------------------------------------------------------------------
__global__ void k_fill(const int* __restrict__ src, const int* __restrict__ dst,
                       int* __restrict__ deg, int* __restrict__ csr) {
    int i = blockIdx.x * blockDim.x + threadIdx.x;   // 131072 threads
    int4 s4 = ((const int4*)src)[i];
    int4 d4 = ((const int4*)dst)[i];
    csr[(d4.x << 6) + atomicAdd(&deg[d4.x], 1)] = s4.x;
    csr[(d4.y << 6) + atomicAdd(&deg[d4.y], 1)] = s4.y;
    csr[(d4.z << 6) + atomicAdd(&deg[d4.z], 1)] = s4.z;
    csr[(d4.w << 6) + atomicAdd(&deg[d4.w], 1)] = s4.w;
}

// ---------------------------------------------------------------------------
// k_layer: FUSED gather + gemm. One block = 64 nodes (512 blocks, 2/CU).
//
// Phase A: gather messages directly into LDS. Wave w owns nodes
//   w*16..w*16+15, processed in PAIRS: 16 row-loads in flight per drain
//   (was 8) -> half the latency-exposed stalls at the 2-waves/SIMD
//   occupancy this kernel runs at. Lane split per node: fg4=(lane&15)*4
//   features, es=lane>>4 slot-group. Two unconditional int4 slot-rounds
//   per node (slots 0..31, covers deg<=32; pad slots hit the L1-hot
//   sentinel row NN = zeros, exact +0.f). Index int4s prefetched one
//   PAIR ahead. Rare deg>32 tail (P~1.5e-4) via wave-uniform branch.
//   Per-node summation order identical to the unpaired version.
//
// Phase B: hn[n][o] = normalize(relu(sum_kk X[n][kk]*Wc[kk][o] + c[o])),
//   X = [m | h], thread tile 4n x 4o.
// ---------------------------------------------------------------------------
__global__ void __launch_bounds__(256) k_layer(
        const float* __restrict__ Wc, const float* __restrict__ hcur,
        const int* __restrict__ deg, const int* __restrict__ csr,
        float* __restrict__ hnext) {
    __shared__ float Wl[8192];       // [kk][o], stride 64
    __shared__ float Xl[64 * 132];   // [n][kk], stride 132
    int t = threadIdx.x;
    int nbase = blockIdx.x * 64;

    int w = t >> 6, lane = t & 63;
    int fg4 = (lane & 15) * 4, es = lane >> 4;
    int nb = nbase + w * 16;
    const int4* base4 = (const int4*)csr + (long)nb * 16;
    // issue pair-0 index loads first so they are in flight during staging
    int4 iA0 = base4[es];
    int4 iB0 = base4[4 + es];
    int4 iA1 = base4[16 + es];
    int4 iB1 = base4[20 + es];
    int dv = deg[nb + (lane & 15)];          // 16 degs, one coalesced line

    for (int i = t * 4; i < 8192; i += 1024)
        *(float4*)&Wl[i] = *(const float4*)&Wc[i];
    for (int idx = t; idx < 1024; idx += 256) {
        int n = idx >> 4, c = (idx & 15) * 4;
        *(float4*)&Xl[n*132 + 64 + c] = *(const float4*)&hcur[(long)(nbase+n)*64 + c];
    }

    // ---- Phase A: gather messages into Xl[n][0..63], node pairs ----
    for (int ni = 0; ni < 16; ni += 2) {
        int4 cA0 = iA0, cB0 = iB0, cA1 = iA1, cB1 = iB1;
        if (ni < 14) {                       // prefetch next pair's indices
            iA0 = base4[(ni+2)*16 + es];
            iB0 = base4[(ni+2)*16 + 4 + es];
            iA1 = base4[(ni+3)*16 + es];
            iB1 = base4[(ni+3)*16 + 4 + es];
        }
        float4 a0 = *(const float4*)&hcur[(long)cA0.x*64 + fg4];
        float4 a1 = *(const float4*)&hcur[(long)cA0.y*64 + fg4];
        float4 a2 = *(const float4*)&hcur[(long)cA0.z*64 + fg4];
        float4 a3 = *(const float4*)&hcur[(long)cA0.w*64 + fg4];
        float4 b0 = *(const float4*)&hcur[(long)cB0.x*64 + fg4];
        float4 b1 = *(const float4*)&hcur[(long)cB0.y*64 + fg4];
        float4 b2 = *(const float4*)&hcur[(long)cB0.z*64 + fg4];
        float4 b3 = *(const float4*)&hcur[(long)cB0.w*64 + fg4];
        float4 c0 = *(const float4*)&hcur[(long)cA1.x*64 + fg4];
        float4 c1 = *(const float4*)&hcur[(long)cA1.y*64 + fg4];
        float4 c2 = *(const float4*)&hcur[(long)cA1.z*64 + fg4];
        float4 c3 = *(const float4*)&hcur[(long)cA1.w*64 + fg4];
        float4 d0 = *(const float4*)&hcur[(long)cB1.x*64 + fg4];
        float4 d1 = *(const float4*)&hcur[(long)cB1.y*64 + fg4];
        float4 d2 = *(const float4*)&hcur[(long)cB1.z*64 + fg4];
        float4 d3 = *(const float4*)&hcur[(long)cB1.w*64 + fg4];
        float4 s0, s1;
        s0.x = ((a0.x + a1.x) + (a2.x + a3.x)) + ((b0.x + b1.x) + (b2.x + b3.x));
        s0.y = ((a0.y + a1.y) + (a2.y + a3.y)) + ((b0.y + b1.y) + (b2.y + b3.y));
        s0.z = ((a0.z + a1.z) + (a2.z + a3.z)) + ((b0.z + b1.z) + (b2.z + b3.z));
        s0.w = ((a0.w + a1.w) + (a2.w + a3.w)) + ((b0.w + b1.w) + (b2.w + b3.w));
        s1.x = ((c0.x + c1.x) + (c2.x + c3.x)) + ((d0.x + d1.x) + (d2.x + d3.x));
        s1.y = ((c0.y + c1.y) + (c2.y + c3.y)) + ((d0.y + d1.y) + (d2.y + d3.y));
        s1.z = ((c0.z + c1.z) + (c2.z + c3.z)) + ((d0.z + d1.z) + (d2.z + d3.z));
        s1.w = ((c0.w + c1.w) + (c2.w + c3.w)) + ((d0.w + d1.w) + (d2.w + d3.w));
        int dg0 = __shfl(dv, ni, 64);
        int dg1 = __shfl(dv, ni + 1, 64);
        if (dg0 > 32) {                      // rare exact tail (deg 33..64)
            int de4 = (dg0 + 3) >> 2;
            for (int q = es + 8; q < de4; q += 4) {
                int4 cx = base4[ni*16 + q];
                float4 v0 = *(const float4*)&hcur[(long)cx.x*64 + fg4];
                float4 v1 = *(const float4*)&hcur[(long)cx.y*64 + fg4];
                float4 v2 = *(const float4*)&hcur[(long)cx.z*64 + fg4];
                float4 v3 = *(const float4*)&hcur[(long)cx.w*64 + fg4];
                s0.x += (v0.x + v1.x) + (v2.x + v3.x);
                s0.y += (v0.y + v1.y) + (v2.y + v3.y);
                s0.z += (v0.z + v1.z) + (v2.z + v3.z);
                s0.w += (v0.w + v1.w) + (v2.w + v3.w);
            }
        }
        if (dg1 > 32) {
            int de4 = (dg1 + 3) >> 2;
            for (int q = es + 8; q < de4; q += 4) {
                int4 cx = base4[(ni+1)*16 + q];
                float4 v0 = *(const float4*)&hcur[(long)cx.x*64 + fg4];
                float4 v1 = *(const float4*)&hcur[(long)cx.y*64 + fg4];
                float4 v2 = *(const float4*)&hcur[(long)cx.z*64 + fg4];
                float4 v3 = *(const float4*)&hcur[(long)cx.w*64 + fg4];
                s1.x += (v0.x + v1.x) + (v2.x + v3.x);
                s1.y += (v0.y + v1.y) + (v2.y + v3.y);
                s1.z += (v0.z + v1.z) + (v2.z + v3.z);
                s1.w += (v0.w + v1.w) + (v2.w + v3.w);
            }
        }
        s0.x += __shfl_xor(s0.x, 16, 64); s0.y += __shfl_xor(s0.y, 16, 64);
        s0.z += __shfl_xor(s0.z, 16, 64); s0.w += __shfl_xor(s0.w, 16, 64);
        s0.x += __shfl_xor(s0.x, 32, 64); s0.y += __shfl_xor(s0.y, 32, 64);
        s0.z += __shfl_xor(s0.z, 32, 64); s0.w += __shfl_xor(s0.w, 32, 64);
        s1.x += __shfl_xor(s1.x, 16, 64); s1.y += __shfl_xor(s1.y, 16, 64);
        s1.z += __shfl_xor(s1.z, 16, 64); s1.w += __shfl_xor(s1.w, 16, 64);
        s1.x += __shfl_xor(s1.x, 32, 64); s1.y += __shfl_xor(s1.y, 32, 64);
        s1.z += __shfl_xor(s1.z, 32, 64); s1.w += __shfl_xor(s1.w, 32, 64);
        if (es == 0) {
            *(float4*)&Xl[(w*16 + ni    )*132 + fg4] = s0;
            *(float4*)&Xl[(w*16 + ni + 1)*132 + fg4] = s1;
        }
    }
    __syncthreads();

    // ---- Phase B: gemm ----
    int tc = t & 15, tr = t >> 4;
    int o0 = tc * 4, n0 = tr * 4;
    float4 c4 = *(const float4*)&Wc[8192 + o0];
    float acc[4][4] = {};
    #pragma unroll 2
    for (int kk = 0; kk < 128; kk += 4) {
        float4 w0 = *(float4*)&Wl[(kk+0)*64 + o0];
        float4 w1 = *(float4*)&Wl[(kk+1)*64 + o0];
        float4 w2 = *(float4*)&Wl[(kk+2)*64 + o0];
        float4 w3 = *(float4*)&Wl[(kk+3)*64 + o0];
        #pragma unroll
        for (int jn = 0; jn < 4; ++jn) {
            float4 xv = *(float4*)&Xl[(n0+jn)*132 + kk];
            acc[jn][0] += xv.x*w0.x + xv.y*w1.x + xv.z*w2.x + xv.w*w3.x;
            acc[jn][1] += xv.x*w0.y + xv.y*w1.y + xv.z*w2.y + xv.w*w3.y;
            acc[jn][2] += xv.x*w0.z + xv.y*w1.z + xv.z*w2.z + xv.w*w3.z;
            acc[jn][3] += xv.x*w0.w + xv.y*w1.w + xv.z*w2.w + xv.w*w3.w;
        }
    }

    #pragma unroll
    for (int jn = 0; jn < 4; ++jn) {
        float v0 = fmaxf(acc[jn][0] + c4.x, 0.f);
        float v1 = fmaxf(acc[jn][1] + c4.y, 0.f);
        float v2 = fmaxf(acc[jn][2] + c4.z, 0.f);
        float v3 = fmaxf(acc[jn][3] + c4.w, 0.f);
        float ss = v0*v0 + v1*v1 + v2*v2 + v3*v3;
        ss += __shfl_xor(ss, 1, 64);
        ss += __shfl_xor(ss, 2, 64);
        ss += __shfl_xor(ss, 4, 64);
        ss += __shfl_xor(ss, 8, 64);
        float r = 1.0f / sqrtf(ss);
        float4 outv = make_float4(v0*r, v1*r, v2*r, v3*r);
        *(float4*)&hnext[(long)(nbase + n0 + jn)*64 + o0] = outv;
    }
}

// ---------------------------------------------------------------------------
// k_tmat: Tt[g][i*64+o] = sum_j W5[o][i*64+j] * last[g][j].
// 256 blocks = 16 consecutive rows r = i*64+o each; thread = graph.
// ---------------------------------------------------------------------------
__global__ void __launch_bounds__(256) k_tmat(
        const float* __restrict__ h, const float* __restrict__ W5,
        float* __restrict__ Tt) {
    __shared__ float lastL[256 * 65];   // 66.6 KB
    __shared__ float wL[64 * 16];       // [j][rr]
    __shared__ float tr[16 * 257];      // [rr][g]
    int t = threadIdx.x;
    int rb = blockIdx.x * 16;
    int i = rb >> 6, obase = rb & 63;

    for (int idx4 = t; idx4 < 4096; idx4 += 256) {
        int g = idx4 >> 4, c = (idx4 & 15) * 4;
        *(float4*)&lastL[g*65 + c] =
            *(const float4*)&h[((long)g*128 + 127)*64 + c];
    }
    {   // stage W5 slice, transposed to [j][rr]
        int rr = t & 15, j0 = (t >> 4) * 4;
        float4 w = *(const float4*)&W5[(long)(obase + rr)*4096 + i*64 + j0];
        wL[(j0+0)*16 + rr] = w.x;
        wL[(j0+1)*16 + rr] = w.y;
        wL[(j0+2)*16 + rr] = w.z;
        wL[(j0+3)*16 + rr] = w.w;
    }
    __syncthreads();

    int g = t;
    float acc[16] = {};
    for (int j = 0; j < 64; ++j) {
        float lv = lastL[g*65 + j];
        #pragma unroll
        for (int r4 = 0; r4 < 4; ++r4) {
            float4 wv = *(float4*)&wL[j*16 + r4*4];
            acc[r4*4+0] += wv.x * lv;
            acc[r4*4+1] += wv.y * lv;
            acc[r4*4+2] += wv.z * lv;
            acc[r4*4+3] += wv.w * lv;
        }
    }
    #pragma unroll
    for (int rr = 0; rr < 16; ++rr) tr[rr*257 + g] = acc[rr];
    __syncthreads();
    for (int it = 0; it < 4; ++it) {
        int idx = t + it*256;
        int g2 = idx >> 2, c4 = idx & 3;
        float4 v = make_float4(tr[(c4*4+0)*257 + g2], tr[(c4*4+1)*257 + g2],
                               tr[(c4*4+2)*257 + g2], tr[(c4*4+3)*257 + g2]);
        *(float4*)&Tt[(long)g2*4096 + rb + c4*4] = v;
    }
}

// ---------------------------------------------------------------------------
// k_readout: TWO blocks per graph (512 blocks, 2/CU -> 8 waves/CU for
// LDS-latency hiding; was 1 block/CU, 4 waves). Each block does 2 p-tiles.
// T and Wd1t staged per block (duplicate stage ~12 MB total, L2-hot).
// ---------------------------------------------------------------------------
__global__ void __launch_bounds__(256) k_readout(
        const float* __restrict__ h, const float* __restrict__ Tt,
        const float* __restrict__ b5, const float* __restrict__ Wd1t,
        const float* __restrict__ bd1, const float* __restrict__ Wd2,
        const float* __restrict__ bd2, float* __restrict__ out) {
    __shared__ float Tl[4096];       // [i][o], stride 64
    __shared__ float W1t[8192];      // [o][q], stride 128
    __shared__ float OY[32 * 68];    // [p][i] then [p][o], stride 68
    int t = threadIdx.x;
    int g = blockIdx.x >> 1;
    int tile0 = (blockIdx.x & 1) * 2;

    for (int i = t * 4; i < 4096; i += 1024)
        *(float4*)&Tl[i] = *(const float4*)&Tt[(long)g*4096 + i];
    for (int i = t * 4; i < 8192; i += 1024)
        *(float4*)&W1t[i] = *(const float4*)&Wd1t[i];

    int tc = t & 15, tr = t >> 4;      // GEMM1 map
    int o0 = tc * 4, p0 = tr * 2;
    int tc2 = t & 31, tr2 = t >> 5;    // GEMM2 map
    int q0 = tc2 * 4, pp0 = tr2 * 4;
    float4 b5_4  = *(const float4*)&b5[o0];
    float4 bd1_4 = *(const float4*)&bd1[q0];
    float4 wd2_4 = *(const float4*)&Wd2[q0];
    float bd2v = bd2[0];

    for (int pt = 0; pt < 2; ++pt) {
        int pbase = (tile0 + pt) * 32;
        __syncthreads();  // previous tile's GEMM2 reads done; T/W1t staged
        for (int idx = t; idx < 512; idx += 256) {
            int p = idx >> 4, c = (idx & 15) * 4;
            *(float4*)&OY[p*68 + c] =
                *(const float4*)&h[((long)g*128 + pbase + p)*64 + c];
        }
        __syncthreads();

        // GEMM1
        float a10[4] = {0.f,0.f,0.f,0.f};
        float a11[4] = {0.f,0.f,0.f,0.f};
        #pragma unroll 4
        for (int i = 0; i < 64; i += 4) {
            float4 w0 = *(float4*)&Tl[(i+0)*64 + o0];
            float4 w1 = *(float4*)&Tl[(i+1)*64 + o0];
            float4 w2 = *(float4*)&Tl[(i+2)*64 + o0];
            float4 w3 = *(float4*)&Tl[(i+3)*64 + o0];
            float4 x0 = *(float4*)&OY[(p0+0)*68 + i];
            float4 x1 = *(float4*)&OY[(p0+1)*68 + i];
            a10[0] += x0.x*w0.x + x0.y*w1.x + x0.z*w2.x + x0.w*w3.x;
            a10[1] += x0.x*w0.y + x0.y*w1.y + x0.z*w2.y + x0.w*w3.y;
            a10[2] += x0.x*w0.z + x0.y*w1.z + x0.z*w2.z + x0.w*w3.z;
            a10[3] += x0.x*w0.w + x0.y*w1.w + x0.z*w2.w + x0.w*w3.w;
            a11[0] += x1.x*w0.x + x1.y*w1.x + x1.z*w2.x + x1.w*w3.x;
            a11[1] += x1.x*w0.y + x1.y*w1.y + x1.z*w2.y + x1.w*w3.y;
            a11[2] += x1.x*w0.z + x1.y*w1.z + x1.z*w2.z + x1.w*w3.z;
            a11[3] += x1.x*w0.w + x1.y*w1.w + x1.z*w2.w + x1.w*w3.w;
        }
        __syncthreads();  // all reads of O done; OY becomes Y

        float4 y0 = make_float4(a10[0]+b5_4.x, a10[1]+b5_4.y, a10[2]+b5_4.z, a10[3]+b5_4.w);
        float4 y1 = make_float4(a11[0]+b5_4.x, a11[1]+b5_4.y, a11[2]+b5_4.z, a11[3]+b5_4.w);
        *(float4*)&OY[(p0+0)*68 + o0] = y0;
        *(float4*)&OY[(p0+1)*68 + o0] = y1;
        __syncthreads();

        // GEMM2
        float a2[4][4] = {};
        #pragma unroll 4
        for (int o = 0; o < 64; o += 4) {
            float4 w0 = *(float4*)&W1t[(o+0)*128 + q0];
            float4 w1 = *(float4*)&W1t[(o+1)*128 + q0];
            float4 w2 = *(float4*)&W1t[(o+2)*128 + q0];
            float4 w3 = *(float4*)&W1t[(o+3)*128 + q0];
            #pragma unroll
            for (int jp = 0; jp < 4; ++jp) {
                float4 yv = *(float4*)&OY[(pp0+jp)*68 + o];
                a2[jp][0] += yv.x*w0.x + yv.y*w1.x + yv.z*w2.x + yv.w*w3.x;
                a2[jp][1] += yv.x*w0.y + yv.y*w1.y + yv.z*w2.y + yv.w*w3.y;
                a2[jp][2] += yv.x*w0.z + yv.y*w1.z + yv.z*w2.z + yv.w*w3.z;
                a2[jp][3] += yv.x*w0.w + yv.y*w1.w + yv.z*w2.w + yv.w*w3.w;
            }
        }

        #pragma unroll
        for (int jp = 0; jp < 4; ++jp) {
            float s = wd2_4.x * fmaxf(a2[jp][0] + bd1_4.x, 0.f)
                    + wd2_4.y * fmaxf(a2[jp][1] + bd1_4.y, 0.f)
                    + wd2_4.z * fmaxf(a2[jp][2] + bd1_4.z, 0.f)
                    + wd2_4.w * fmaxf(a2[jp][3] + bd1_4.w, 0.f);
            s += __shfl_xor(s, 1, 64);
            s += __shfl_xor(s, 2, 64);
            s += __shfl_xor(s, 4, 64);
            s += __shfl_xor(s, 8, 64);
            s += __shfl_xor(s, 16, 64);
            if (tc2 == 0) {
                int p = pbase + pp0 + jp;
                if (p < 127) out[g*127 + p] = s + bd2v;
            }
        }
    }
}

extern "C" void kernel_launch(void* const* d_in, const int* in_sizes, int n_in,
                              void* d_out, int out_size, void* d_ws, size_t ws_size,
                              hipStream_t stream) {
    const float* x   = (const float*)d_in[0];
    const int*   ei  = (const int*)d_in[1];   // [2][E] int32
    const float* W1  = (const float*)d_in[4];
    const float* b1  = (const float*)d_in[5];
    const float* W2  = (const float*)d_in[6];
    const float* b2  = (const float*)d_in[7];
    const float* W3  = (const float*)d_in[8];
    const float* b3  = (const float*)d_in[9];
    const float* W4  = (const float*)d_in[10];
    const float* b4  = (const float*)d_in[11];
    const float* W5  = (const float*)d_in[12];
    const float* b5  = (const float*)d_in[13];
    const float* Wd1 = (const float*)d_in[14];
    const float* bd1 = (const float*)d_in[15];
    const float* Wd2 = (const float*)d_in[16];
    const float* bd2 = (const float*)d_in[17];
    float* out = (float*)d_out;

    float* ws  = (float*)d_ws;
    float* h0   = ws;                        // (NN+1)*64 floats (row NN = zeros)
    float* h1   = ws + 2129984;              // (NN+1)*64 floats, 16-aligned
    float* Tt   = ws + 4259968;              // 2^20 floats
    float* Wc   = ws + 5308416;              // 8448 floats
    float* Wd1t = ws + 5316864;              // 8192 floats
    int*   deg  = (int*)(ws + 5325056);      // NN
    int*   csr  = deg + NN;                  // NN*64 ints (bucket CSR)

    const int* src = ei;
    const int* dst = ei + EE;

    k_init<<<8226, 256, 0, stream>>>(x, W1, b1, W2, b2, W3, b3, W4, b4,
                                     Wd1, h0, h1, Wc, Wd1t, deg, csr);
    k_fill<<<512, 256, 0, stream>>>(src, dst, deg, csr);

    float* hc = h0; float* hn = h1;
    for (int l = 0; l < 3; ++l) {
        k_layer<<<NN/64, 256, 0, stream>>>(Wc, hc, deg, csr, hn);
        float* tmp = hc; hc = hn; hn = tmp;
    }

    k_tmat<<<256, 256, 0, stream>>>(hc, W5, Tt);
    k_readout<<<512, 256, 0, stream>>>(hc, Tt, b5, Wd1t, bd1, Wd2, bd2, out);
}